// Round 10
// baseline (28.391 us; speedup 1.0000x reference)
//
#include <hip/hip_runtime.h>

// Capsule agreement routing, fp32.
// preds [8,32,14,14,32,16], b [1,32,14,14,32], out v [8,32,14,14,16].
//
// 8 sites per 64-lane wave; lane (s_w = lane>>3, g = lane&7) owns rows
// i = g + 8k (k=0..3) x all 16 d of site s_w -> p[4][4] = 64 VGPRs.
// Small footprint + DMA staging => fits __launch_bounds__(256,4):
// 4 blocks/CU x 4 waves = 16 waves/CU (2x the R4/R8 occupancy) to hide
// the latency-bound serial routing passes.
//
// Staging: global_load_lds (OFF=0, runtime addresses only -- the R9
// immediate-offset experiment is abandoned), 4 row-phases of 4 KB
// (phase ph = rows [8ph, 8ph+8) of all 8 sites), double-buffered A/B
// (8 KB/wave, 32 KB/block), counted vmcnt(4) per phase, vmcnt(0) only at
// the tail. Stride-8 row ownership => every phase gives EVERY lane exactly
// one row: all ds_reads are full-wave b128, no exec masking (R6's flaw).
//
// XOR swizzle both-sides (LDS dest linear, source pre-swizzled):
//   site x phase-local f4 m = j*4+u (j=row&7, u comp) stored at slot
//   x*32 + (m ^ x); DMA src f4 = x*128 + 32*ph + (m ^ x).
//   Verified: (x=5,i=13,u=2): slot 179 <- src f4 694 = direct index. ✓
//   read (fixed u): slot = s_w*32 + ((4g+u) ^ s_w); bank-group
//   (4(g&1)+u) ^ s_w -> exactly 8 lanes/group = b128 data-rate floor.
//
// Math per pass (cross-lane = quad_perm + row_half_mirror DPP, zero
// LDS-pipe ops; 8-lane site groups are aligned, mirror = xor 7 on 3 bits):
//   b in log2 domain -> e = exp2(bl), fused into the s-accumulate
//   softmax sum: 3 local adds + 3 DPP; r = rcp(sum) folded into squash
//   s~_d = sum_i e_i p_id : 64 lane-local FMA + 3-DPP reduce per comp
//   squash: sq = r^2|s~|^2, f = sq/(1+sq)/sqrt(sq+eps)*r ; v = f*s~
//   agreement: bl_k += (f*log2e) * dot(p_k, s~) -- fully lane-local

#define EPSQ 1e-7f
#define LOG2E 1.442695041f

constexpr int OHW   = 6272;           // 32*14*14
constexpr int SITES = 50176;          // 8 * OHW
constexpr int THREADS = 256;
constexpr int BLOCKS  = SITES / 32;   // 1568 (8 sites/wave * 4 waves/block)

__device__ __forceinline__ float dpp1(float x) {   // quad_perm xor 1
    return __int_as_float(__builtin_amdgcn_mov_dpp(__float_as_int(x), 0xB1, 0xF, 0xF, true));
}
__device__ __forceinline__ float dpp2(float x) {   // quad_perm xor 2
    return __int_as_float(__builtin_amdgcn_mov_dpp(__float_as_int(x), 0x4E, 0xF, 0xF, true));
}
__device__ __forceinline__ float dpp4(float x) {   // row_half_mirror: l -> l^7 in each 8
    return __int_as_float(__builtin_amdgcn_mov_dpp(__float_as_int(x), 0x141, 0xF, 0xF, true));
}
__device__ __forceinline__ void fma4(float4& a, float c, const float4& x) {
    a.x = fmaf(c, x.x, a.x); a.y = fmaf(c, x.y, a.y);
    a.z = fmaf(c, x.z, a.z); a.w = fmaf(c, x.w, a.w);
}
__device__ __forceinline__ float dot4(const float4& a, const float4& b) {
    return fmaf(a.x, b.x, fmaf(a.y, b.y, fmaf(a.z, b.z, a.w * b.w)));
}
__device__ __forceinline__ void red8_4(float4& a) {
    a.x += dpp1(a.x); a.y += dpp1(a.y); a.z += dpp1(a.z); a.w += dpp1(a.w);
    a.x += dpp2(a.x); a.y += dpp2(a.y); a.z += dpp2(a.z); a.w += dpp2(a.w);
    a.x += dpp4(a.x); a.y += dpp4(a.y); a.z += dpp4(a.z); a.w += dpp4(a.w);
}

__device__ __forceinline__ void gload16(const char* g, float4* l) {
    __builtin_amdgcn_global_load_lds(
        (const __attribute__((address_space(1))) void*)g,
        (__attribute__((address_space(3))) void*)l, 16, 0, 0);
}

__global__ __launch_bounds__(256, 4) void routing_kernel(
    const float* __restrict__ preds,
    const float* __restrict__ bparam,
    float* __restrict__ out)
{
    __shared__ float4 lds4[2048];     // 32 KB = 4 waves x (2 bufs x 256 f4)
    const int tid  = threadIdx.x;
    const int lane = tid & 63;
    const int wib  = tid >> 6;
    const int wave = blockIdx.x * 4 + wib;
    const int g    = lane & 7;        // row class: rows g, g+8, g+16, g+24
    const int s_w  = lane >> 3;       // within-wave site 0..7
    const int site = wave * 8 + s_w;

    float4* bufA = lds4 + wib * 512;
    float4* bufB = bufA + 256;
    const char* pgc = (const char*)((const float4*)preds + (size_t)wave * 1024);

    // ---- routing logits FIRST (oldest 4 entries in the vmcnt queue)
    const int sohw = site % OHW;
    const float* bs = bparam + (size_t)sohw * 32 + g;
    float bl[4];
    #pragma unroll
    for (int k = 0; k < 4; ++k) bl[k] = bs[8 * k];
    asm volatile("" ::: "memory");    // pin b-loads ahead of the DMA queue

    // ---- per-lane DMA source offsets (bytes), phase 0:
    // instr t covers LDS slots [t*64, t*64+64); pos = t*64+lane;
    // x = 2t + (lane>>5), w = pos&31 = lane&31; src f4 = x*128 + (w ^ x)
    const int hi  = lane >> 5;
    const int w32 = lane & 31;
    int vofs[4];
    #pragma unroll
    for (int t = 0; t < 4; ++t) {
        const int x = 2 * t + hi;
        vofs[t] = (x * 128 + (w32 ^ x)) * 16;
    }

    // ---- prologue: ph0 -> A, ph1 -> B  (phase stride = 32 f4 = 512 B)
    #pragma unroll
    for (int t = 0; t < 4; ++t) gload16(pgc + vofs[t], bufA + t * 64);
    #pragma unroll
    for (int t = 0; t < 4; ++t) gload16(pgc + vofs[t] + 512, bufB + t * 64);

    float4 p[4][4];                   // p[k][u] = row g+8k, comps 4u..4u+3
    const int rbase = s_w * 32;
    const int rkey  = s_w;

    auto read_ph = [&](int k, const float4* buf) {
        #pragma unroll
        for (int u = 0; u < 4; ++u)
            p[k][u] = buf[rbase + ((4 * g + u) ^ rkey)];
    };

    // ---- counted-vmcnt pipeline (R8 discipline, OFF=0 addresses)
    asm volatile("s_waitcnt vmcnt(4)" ::: "memory");    // b + ph0 landed
    read_ph(0, bufA);
    asm volatile("s_waitcnt lgkmcnt(0)" ::: "memory");  // A drained to regs
    #pragma unroll
    for (int t = 0; t < 4; ++t) gload16(pgc + vofs[t] + 1024, bufA + t * 64); // ph2

    asm volatile("s_waitcnt vmcnt(4)" ::: "memory");    // ph1 landed
    read_ph(1, bufB);
    asm volatile("s_waitcnt lgkmcnt(0)" ::: "memory");  // B drained to regs
    #pragma unroll
    for (int t = 0; t < 4; ++t) gload16(pgc + vofs[t] + 1536, bufB + t * 64); // ph3

    asm volatile("s_waitcnt vmcnt(4)" ::: "memory");    // ph2 landed
    read_ph(2, bufA);
    asm volatile("s_waitcnt vmcnt(0)" ::: "memory");    // ph3 landed
    read_ph(3, bufB);

    // logits -> log2 domain
    #pragma unroll
    for (int k = 0; k < 4; ++k) bl[k] *= LOG2E;

    float4 s0, s1, s2, s3;            // unnormalized s~, replicated across site
    float  f;                         // v = f * s~

    auto pass = [&]() {
        float sm = 0.0f;
        s0 = make_float4(0,0,0,0); s1 = make_float4(0,0,0,0);
        s2 = make_float4(0,0,0,0); s3 = make_float4(0,0,0,0);
        #pragma unroll
        for (int k = 0; k < 4; ++k) {
            const float e = __builtin_amdgcn_exp2f(bl[k]);
            sm += e;
            fma4(s0, e, p[k][0]); fma4(s1, e, p[k][1]);
            fma4(s2, e, p[k][2]); fma4(s3, e, p[k][3]);
        }
        sm += dpp1(sm);
        sm += dpp2(sm);
        sm += dpp4(sm);
        const float r = __frcp_rn(sm);
        red8_4(s0); red8_4(s1); red8_4(s2); red8_4(s3);

        const float sqt = dot4(s0, s0) + dot4(s1, s1) + dot4(s2, s2) + dot4(s3, s3);
        const float sq  = r * r * sqt;
        f = sq * __frcp_rn(1.0f + sq) * __frsqrt_rn(sq + EPSQ) * r;
    };

    pass();

    #pragma unroll
    for (int it = 0; it < 3; ++it) {
        const float fl = f * LOG2E;
        #pragma unroll
        for (int k = 0; k < 4; ++k) {
            const float qk = dot4(p[k][0], s0) + dot4(p[k][1], s1)
                           + dot4(p[k][2], s2) + dot4(p[k][3], s3);
            bl[k] = fmaf(fl, qk, bl[k]);
        }
        pass();
    }

    // epilogue: s~ replicated across the site's 8 lanes; lanes g<4 write
    // one float4 each -> contiguous 512 B per wave
    if (g < 4) {
        float4 wv = (g == 0) ? s0 : (g == 1) ? s1 : (g == 2) ? s2 : s3;
        wv.x *= f; wv.y *= f; wv.z *= f; wv.w *= f;
        ((float4*)out)[(size_t)site * 4 + g] = wv;
    }
}

extern "C" void kernel_launch(void* const* d_in, const int* in_sizes, int n_in,
                              void* d_out, int out_size, void* d_ws, size_t ws_size,
                              hipStream_t stream) {
    const float* preds  = (const float*)d_in[0];
    const float* bparam = (const float*)d_in[1];
    float* out = (float*)d_out;
    routing_kernel<<<BLOCKS, THREADS, 0, stream>>>(preds, bparam, out);
}